// Round 1
// baseline (588.914 us; speedup 1.0000x reference)
//
#include <hip/hip_runtime.h>
#include <hip/hip_bf16.h>
#include <stdint.h>

#define GN 8192
#define GF 128
#define NEG_SLOPE 0.2f

// monotone float<->uint key for atomicMax over signed floats (memset-0 == -inf)
__device__ __forceinline__ unsigned fkey(float f) {
    unsigned u = __float_as_uint(f);
    return (u & 0x80000000u) ? ~u : (u | 0x80000000u);
}
__device__ __forceinline__ float funkey(unsigned k) {
    unsigned b = (k & 0x80000000u) ? (k & 0x7FFFFFFFu) : ~k;
    return __uint_as_float(b);
}

// Kernel 1: x' = x@W + b ; s_src = x'@phi[:F] ; s_dst = x'@phi[F:]
// also: global max of s_dst (for softmax shift), x' stored as bf16 for gathers.
__global__ __launch_bounds__(256) void gat_k1(
    const float* __restrict__ x, const float* __restrict__ w,
    const float* __restrict__ bias, const float* __restrict__ phi,
    unsigned short* __restrict__ xp, float* __restrict__ s_src,
    float* __restrict__ s_dst, unsigned* __restrict__ Dkey)
{
    __shared__ float Wl[GF * GF];   // 64 KB: whole weight matrix
    __shared__ float Xl[16 * GF];   // 8 KB: 16-row x tile
    const int tid = threadIdx.x;
    const int r0 = blockIdx.x * 16;

    {
        const float4* src = (const float4*)w;
        float4* dst = (float4*)Wl;
        for (int idx = tid; idx < GF * GF / 4; idx += 256) dst[idx] = src[idx];
        const float4* xs = (const float4*)(x + (size_t)r0 * GF);
        float4* xd = (float4*)Xl;
        for (int idx = tid; idx < 16 * GF / 4; idx += 256) xd[idx] = xs[idx];
    }
    __syncthreads();

    const int rid = tid >> 5;   // 0..7 -> 2 rows each
    const int cid = tid & 31;   // 0..31 -> 4 cols each
    const int c0 = cid * 4;

    float acc[2][4];
    #pragma unroll
    for (int m = 0; m < 2; m++)
        #pragma unroll
        for (int q = 0; q < 4; q++) acc[m][q] = 0.f;

    for (int k = 0; k < GF; k++) {
        float4 wv = *(const float4*)&Wl[k * GF + c0];
        #pragma unroll
        for (int m = 0; m < 2; m++) {
            float xv = Xl[(rid * 2 + m) * GF + k];  // LDS broadcast across 32 lanes
            acc[m][0] += xv * wv.x;
            acc[m][1] += xv * wv.y;
            acc[m][2] += xv * wv.z;
            acc[m][3] += xv * wv.w;
        }
    }

    float b4[4], p1[4], p2[4];
    #pragma unroll
    for (int q = 0; q < 4; q++) {
        b4[q] = bias[c0 + q];
        p1[q] = phi[c0 + q];
        p2[q] = phi[GF + c0 + q];
    }

    #pragma unroll
    for (int m = 0; m < 2; m++) {
        float ps = 0.f, pd = 0.f;
        unsigned short pk[4];
        #pragma unroll
        for (int q = 0; q < 4; q++) {
            float v = acc[m][q] + b4[q];
            ps += v * p1[q];
            pd += v * p2[q];
            unsigned ub = __float_as_uint(v);   // RNE round to bf16
            pk[q] = (unsigned short)((ub + 0x7FFFu + ((ub >> 16) & 1u)) >> 16);
        }
        // reduce over the 32 lanes that share this row (contiguous half-wave)
        #pragma unroll
        for (int s = 16; s >= 1; s >>= 1) {
            ps += __shfl_xor(ps, s, 64);
            pd += __shfl_xor(pd, s, 64);
        }
        const int row = r0 + rid * 2 + m;
        *(ushort4*)&xp[(size_t)row * GF + c0] =
            make_ushort4(pk[0], pk[1], pk[2], pk[3]);
        if (cid == 0) {
            s_src[row] = ps;
            s_dst[row] = pd;
            atomicMax(Dkey, fkey(pd));
        }
    }
}

// Kernel 2: one block per row i. Single pass: p_ij = keep ? exp(lrelu(s_i+s_j)-Mi) : 0
// with Mi = lrelu(s_i + max_j s_dst[j]) >= rowmax (shift-invariance => exact softmax).
__global__ __launch_bounds__(256) void gat_k2(
    const float* __restrict__ adj, const unsigned short* __restrict__ xp,
    const float* __restrict__ s_src, const float* __restrict__ s_dst,
    const unsigned* __restrict__ Dkey, float* __restrict__ out)
{
    __shared__ float sacc[4][GF];
    __shared__ float szz[4];
    const int i = blockIdx.x;
    const int tid = threadIdx.x;
    const int wave = tid >> 6, lane = tid & 63;

    const float D = funkey(*Dkey);
    const float si = s_src[i];
    const float T = si + D;
    const float Mi = T > 0.f ? T : NEG_SLOPE * T;
    const float* arow = adj + (size_t)i * GN;

    float accx = 0.f, accy = 0.f, Z = 0.f;

    // each wave owns 2048 columns: 8 iterations of 256 (float4 per lane)
    for (int it = 0; it < 8; it++) {
        const int chunk = wave * 2048 + it * 256;      // base of 256-col chunk
        const int jb = chunk + lane * 4;
        float4 a  = *(const float4*)(arow + jb);
        float4 sd = *(const float4*)(s_dst + jb);
        float p[4];
        #pragma unroll
        for (int q = 0; q < 4; q++) {
            const int j = jb + q;
            const float aq = (&a.x)[q];
            const bool keep = (aq > 0.f) || (j == i);
            const float t = si + (&sd.x)[q];
            const float S = t > 0.f ? t : NEG_SLOPE * t;
            const float pv = keep ? __expf(S - Mi) : 0.f;
            p[q] = pv;
            Z += pv;
        }
        #pragma unroll
        for (int q = 0; q < 4; q++) {
            unsigned long long m = __ballot(p[q] > 0.f);
            while (m) {  // wave-uniform sparse loop (~3 set bits avg)
                const int l = __ffsll(m) - 1;
                m &= m - 1;
                const float pj = __shfl(p[q], l, 64);
                const int j = chunk + l * 4 + q;
                // 64 lanes gather the full 128-feat bf16 row of x'[j], 2 feats/lane
                const unsigned u = *(const unsigned*)&xp[(size_t)j * GF + lane * 2];
                accx += pj * __uint_as_float(u << 16);
                accy += pj * __uint_as_float(u & 0xFFFF0000u);
            }
        }
    }

    #pragma unroll
    for (int s = 32; s >= 1; s >>= 1) Z += __shfl_xor(Z, s, 64);
    sacc[wave][lane * 2]     = accx;
    sacc[wave][lane * 2 + 1] = accy;
    if (lane == 0) szz[wave] = Z;
    __syncthreads();

    if (tid < GF) {
        const float h = sacc[0][tid] + sacc[1][tid] + sacc[2][tid] + sacc[3][tid];
        const float Zs = szz[0] + szz[1] + szz[2] + szz[3];
        out[(size_t)i * GF + tid] = h / Zs;
    }
}

extern "C" void kernel_launch(void* const* d_in, const int* in_sizes, int n_in,
                              void* d_out, int out_size, void* d_ws, size_t ws_size,
                              hipStream_t stream)
{
    (void)in_sizes; (void)n_in; (void)out_size; (void)ws_size;
    const float* adj  = (const float*)d_in[0];
    const float* x    = (const float*)d_in[1];
    const float* w    = (const float*)d_in[2];
    const float* bias = (const float*)d_in[3];
    const float* phi  = (const float*)d_in[4];
    float* out = (float*)d_out;

    char* ws = (char*)d_ws;
    unsigned short* xp = (unsigned short*)ws;                 // 2 MB bf16 x'
    float* s_src = (float*)(ws + (size_t)GN * GF * 2);        // 32 KB
    float* s_dst = s_src + GN;                                // 32 KB
    unsigned* Dkey = (unsigned*)(s_dst + GN);                 // 4 B

    hipMemsetAsync(Dkey, 0, sizeof(unsigned), stream);
    gat_k1<<<GN / 16, 256, 0, stream>>>(x, w, bias, phi, xp, s_src, s_dst, Dkey);
    gat_k2<<<GN, 256, 0, stream>>>(adj, xp, s_src, s_dst, Dkey, out);
}